// Round 2
// baseline (3013.567 us; speedup 1.0000x reference)
//
#include <hip/hip_runtime.h>
#include <hip/hip_cooperative_groups.h>

namespace cg = cooperative_groups;

#define B 4
#define C 64
#define T 256
#define A 4096
#define KS 8          // atom length
#define RC 264        // residual columns = T + KS
#define PW 260        // fm position stride (257 real, 3 sentinel)
#define NITER 32

// ---------------- workspace layout (bytes) ----------------
#define WS_DN     0            // A*512 f32          = 8,388,608
#define WS_RES    8388608      // B*C*RC f32         =   270,336
#define WS_RECON  8658944      // B*C*RC f32         =   270,336
#define WS_FM     8929280      // B*A*PW f32         = 17,039,360
#define WS_PART   25968640     // 4*256 u64          =     8,192

__device__ inline unsigned long long packmax(float v, unsigned key) {
    unsigned u = __float_as_uint(v);
    u = (u & 0x80000000u) ? ~u : (u | 0x80000000u);   // monotonic float->uint
    return ((unsigned long long)u << 32) | (unsigned long long)(0xFFFFFFFFu - key);
}

// ---------------- K1: unit-norm the dictionary ----------------
__global__ void k_norm(const float* __restrict__ d, float* __restrict__ dn) {
    const int atom = blockIdx.x * 4 + (threadIdx.x >> 6);
    const int lane = threadIdx.x & 63;
    const float* src = d + atom * 512;
    float4 v0 = ((const float4*)src)[lane * 2];
    float4 v1 = ((const float4*)src)[lane * 2 + 1];
    float s = v0.x*v0.x + v0.y*v0.y + v0.z*v0.z + v0.w*v0.w
            + v1.x*v1.x + v1.y*v1.y + v1.z*v1.z + v1.w*v1.w;
    #pragma unroll
    for (int off = 32; off; off >>= 1) s += __shfl_xor(s, off);
    const float denom = sqrtf(s) + 1e-8f;
    float* dst = dn + atom * 512;
    float4 o0 = make_float4(v0.x/denom, v0.y/denom, v0.z/denom, v0.w/denom);
    float4 o1 = make_float4(v1.x/denom, v1.y/denom, v1.z/denom, v1.w/denom);
    ((float4*)dst)[lane * 2]     = o0;
    ((float4*)dst)[lane * 2 + 1] = o1;
}

// ---------------- K2: init res (padded x), recon=0, fm=-1e30 ----------------
__global__ void k_init(const float* __restrict__ x, float* __restrict__ res,
                       float* __restrict__ recon, float* __restrict__ fm) {
    const int tid = blockIdx.x * blockDim.x + threadIdx.x;
    const int nth = gridDim.x * blockDim.x;
    for (int i = tid; i < B * C * RC; i += nth) {
        const int col = i % RC;
        const int bc  = i / RC;
        res[i]   = (col < T) ? x[bc * T + col] : 0.0f;
        recon[i] = 0.0f;
    }
    for (int i = tid; i < B * A * PW; i += nth) fm[i] = -1e30f;
}

// ---------------- K3: full correlation fm[b][a][p], p=0..256 ----------------
__global__ __launch_bounds__(320) void k_conv(const float* __restrict__ res,
                                              const float* __restrict__ dn,
                                              float* __restrict__ fm) {
    __shared__ __align__(16) float lr[16 * 264];
    __shared__ __align__(16) float ld[16 * 16 * 8];
    const int b  = blockIdx.y;
    const int a0 = blockIdx.x * 16;
    const int t  = threadIdx.x;
    const int wv = t >> 6, ln = t & 63;

    float acc[4][4] = {};
    float acce = 0.0f;

    for (int cb = 0; cb < 4; ++cb) {
        const float* rsrc = res + b * C * RC + cb * 16 * RC;
        for (int i = t; i < 16 * 264; i += 320) lr[i] = rsrc[i];
        const float* dsrc = dn + a0 * 512 + cb * 128;
        for (int i = t; i < 2048; i += 320) {
            const int as = i >> 7, rem = i & 127;
            ld[i] = dsrc[as * 512 + rem];
        }
        __syncthreads();
        if (t < 256) {
            const int p0 = ln * 4;
            for (int cc = 0; cc < 16; ++cc) {
                const float* r = lr + cc * 264 + p0;
                float rv[12];
                *(float4*)(rv)     = *(const float4*)(r);
                *(float4*)(rv + 4) = *(const float4*)(r + 4);
                *(float4*)(rv + 8) = *(const float4*)(r + 8);
                #pragma unroll
                for (int ai = 0; ai < 4; ++ai) {
                    const float* dp = ld + ((wv * 4 + ai) * 16 + cc) * 8;
                    float dk[8];
                    *(float4*)(dk)     = *(const float4*)(dp);
                    *(float4*)(dk + 4) = *(const float4*)(dp + 4);
                    #pragma unroll
                    for (int pi = 0; pi < 4; ++pi)
                        #pragma unroll
                        for (int kk = 0; kk < 8; ++kk)
                            acc[ai][pi] = fmaf(rv[pi + kk], dk[kk], acc[ai][pi]);
                }
            }
        } else {
            const int l = t - 256;
            if ((l & 3) == 0) {
                const int as = l >> 2;
                for (int cc = 0; cc < 16; ++cc)
                    #pragma unroll
                    for (int kk = 0; kk < 8; ++kk)
                        acce = fmaf(lr[cc * 264 + 256 + kk], ld[(as * 16 + cc) * 8 + kk], acce);
            }
        }
        __syncthreads();
    }

    if (t < 256) {
        const int p0 = ln * 4;
        #pragma unroll
        for (int ai = 0; ai < 4; ++ai) {
            float* outp = fm + ((long)b * A + a0 + wv * 4 + ai) * PW + p0;
            float4 o; o.x = acc[ai][0]; o.y = acc[ai][1]; o.z = acc[ai][2]; o.w = acc[ai][3];
            *(float4*)outp = o;
        }
    } else {
        const int l = t - 256;
        if ((l & 3) == 0) fm[((long)b * A + a0 + (l >> 2)) * PW + 256] = acce;
    }
}

// ---------------- K4: fused 32-iteration matching-pursuit loop ----------------
// Cooperative: 256 blocks x 256 threads. Block bk owns atoms [bk*16, bk*16+16).
// Per iteration: Phase S (scan own fm rows -> part; blocks 0..3 commit the
// PREVIOUS delta to res/recon), grid.sync, Phase W (all blocks redundantly
// reduce part -> winners; recompute own fm windows from res with the current
// delta applied locally), grid.sync.
__global__ __launch_bounds__(256) void k_iter(const float* __restrict__ dn,
                                              float* __restrict__ res,
                                              float* __restrict__ recon,
                                              float* __restrict__ fm,
                                              unsigned long long* __restrict__ part) {
    __shared__ __align__(16) float dl[16][512];     // own dictionary slice (persistent)
    __shared__ __align__(16) float wdn[4][512];     // winner atoms per b
    __shared__ __align__(16) float rw[4][64][24];   // res windows per b
    __shared__ unsigned long long sredw[4][4];
    __shared__ int   watom[4], wpos[4];
    __shared__ float wval[4];

    const int bk = blockIdx.x;
    const int a0 = bk * 16;
    const int t  = threadIdx.x;
    cg::grid_group grid = cg::this_grid();

    for (int i = t; i < 16 * 512; i += 256) dl[i >> 9][i & 511] = dn[a0 * 512 + i];
    __syncthreads();

    for (int it = 0; it < NITER; ++it) {
        // ---------------- Phase S ----------------
        if (it > 0 && bk < 4) {
            // commit delta_{it-1} for b = bk (winner info persisted in LDS from prev W)
            const int ca = watom[bk], cp = wpos[bk];
            const float cv = wval[bk];
            const float* dw = dn + (long)ca * 512;
            for (int e = t; e < 512; e += 256) {
                const int c = e >> 3, k = e & 7;
                const float delta = cv * dw[e];
                const long ri = (long)(bk * C + c) * RC + cp + k;
                res[ri]   -= delta;
                recon[ri] += delta;
            }
        }
        // scan own 16 rows for each b
        {
            const int wv = t >> 6;
            for (int b = 0; b < 4; ++b) {
                const float4* pf = (const float4*)(fm + ((long)b * A + a0) * PW);
                unsigned long long m = 0ull;
                for (int i = t; i < 16 * PW / 4; i += 256) {   // 1040 float4
                    const float4 v = pf[i];
                    const unsigned e = (unsigned)(a0 * PW + i * 4);
                    unsigned long long p0 = packmax(v.x, e);
                    unsigned long long p1 = packmax(v.y, e + 1);
                    unsigned long long p2 = packmax(v.z, e + 2);
                    unsigned long long p3 = packmax(v.w, e + 3);
                    if (p1 > p0) p0 = p1;
                    if (p3 > p2) p2 = p3;
                    if (p2 > p0) p0 = p2;
                    if (p0 > m)  m = p0;
                }
                #pragma unroll
                for (int off = 32; off; off >>= 1) {
                    unsigned long long o = __shfl_xor(m, off);
                    if (o > m) m = o;
                }
                if ((t & 63) == 0) sredw[b][wv] = m;
            }
            __syncthreads();
            if (t < 4) {
                unsigned long long m = sredw[t][0];
                if (sredw[t][1] > m) m = sredw[t][1];
                if (sredw[t][2] > m) m = sredw[t][2];
                if (sredw[t][3] > m) m = sredw[t][3];
                part[t * 256 + bk] = m;
            }
        }
        grid.sync();

        // ---------------- Phase W ----------------
        // 1. redundant winner reduce: warp wv handles b = wv
        {
            const int wv = t >> 6, ln = t & 63;
            const unsigned long long* pp = part + wv * 256;
            unsigned long long m = pp[ln];
            unsigned long long o1 = pp[ln + 64], o2 = pp[ln + 128], o3 = pp[ln + 192];
            if (o1 > m) m = o1;
            if (o2 > m) m = o2;
            if (o3 > m) m = o3;
            #pragma unroll
            for (int off = 32; off; off >>= 1) {
                unsigned long long o = __shfl_xor(m, off);
                if (o > m) m = o;
            }
            if (ln == 0) {
                const unsigned key = 0xFFFFFFFFu - (unsigned)(m & 0xFFFFFFFFull);
                unsigned uv = (unsigned)(m >> 32);
                uv = (uv & 0x80000000u) ? (uv & 0x7FFFFFFFu) : ~uv;
                watom[wv] = key / PW;
                wpos[wv]  = key % PW;
                wval[wv]  = __uint_as_float(uv);
            }
        }
        __syncthreads();

        if (it == NITER - 1) {
            // final delta: commit immediately (no res readers remain)
            if (bk < 4) {
                const int ca = watom[bk], cp = wpos[bk];
                const float cv = wval[bk];
                const float* dw = dn + (long)ca * 512;
                for (int e = t; e < 512; e += 256) {
                    const int c = e >> 3, k = e & 7;
                    const float delta = cv * dw[e];
                    const long ri = (long)(bk * C + c) * RC + cp + k;
                    res[ri]   -= delta;
                    recon[ri] += delta;
                }
            }
            break;
        }

        // 2. load winner atoms + res windows; apply current delta locally
        for (int i = t; i < 4 * 512; i += 256) {
            const int b = i >> 9, e = i & 511;
            wdn[b][e] = dn[(long)watom[b] * 512 + e];
        }
        for (int i = t; i < 4 * 64 * 24; i += 256) {
            const int b = i / 1536, r = i % 1536, c = r / 24, j = r % 24;
            const int q = wpos[b];
            int lo = q - 7; if (lo < 0) lo = 0;
            const int col = lo + j;
            rw[b][c][j] = (col < RC) ? res[(long)(b * C + c) * RC + col] : 0.0f;
        }
        __syncthreads();
        for (int i = t; i < 4 * 64 * 8; i += 256) {
            const int b = i >> 9, r = i & 511, c = r >> 3, k = r & 7;
            const int q = wpos[b];
            int lo = q - 7; if (lo < 0) lo = 0;
            const int j = q + k - lo;               // 0..14 < 24
            rw[b][c][j] -= wval[b] * wdn[b][c * 8 + k];
        }
        __syncthreads();

        // 3. recompute fm windows for own 16 atoms
        {
            const int aa = t >> 4, b = (t >> 2) & 3, pt = t & 3;
            const int q = wpos[b];
            int lo = q - 7; if (lo < 0) lo = 0;
            int hi = q + 7; if (hi > 256) hi = 256;
            const int n = hi - lo + 1;
            const int pi0 = pt * 4;
            float acc[4] = {0.f, 0.f, 0.f, 0.f};
            for (int c = 0; c < 64; ++c) {
                float rv[12];
                *(float4*)(rv)     = *(const float4*)&rw[b][c][pi0];
                *(float4*)(rv + 4) = *(const float4*)&rw[b][c][pi0 + 4];
                *(float4*)(rv + 8) = *(const float4*)&rw[b][c][pi0 + 8];
                float dk[8];
                *(float4*)(dk)     = *(const float4*)&dl[aa][c * 8];
                *(float4*)(dk + 4) = *(const float4*)&dl[aa][c * 8 + 4];
                #pragma unroll
                for (int pi = 0; pi < 4; ++pi)
                    #pragma unroll
                    for (int kk = 0; kk < 8; ++kk)
                        acc[pi] = fmaf(rv[pi + kk], dk[kk], acc[pi]);
            }
            float* fb = fm + ((long)b * A + a0 + aa) * PW + lo;
            #pragma unroll
            for (int pi = 0; pi < 4; ++pi) {
                const int p = pi0 + pi;
                if (p < n) fb[p] = acc[pi];
            }
        }
        grid.sync();
    }
}

// ---------------- K7: copy recon[..., :T] to out ----------------
__global__ void k_out(const float* __restrict__ recon, float* __restrict__ out) {
    const int tid = blockIdx.x * blockDim.x + threadIdx.x;
    const int nth = gridDim.x * blockDim.x;
    for (int i = tid; i < B * C * (T / 4); i += nth) {
        const int bc = i >> 6;
        const int c4 = i & 63;
        ((float4*)out)[i] = *(const float4*)&recon[bc * RC + c4 * 4];
    }
}

extern "C" void kernel_launch(void* const* d_in, const int* in_sizes, int n_in,
                              void* d_out, int out_size, void* d_ws, size_t ws_size,
                              hipStream_t stream) {
    const float* x = (const float*)d_in[0];
    const float* d = (const float*)d_in[1];
    char* ws = (char*)d_ws;
    float* dn    = (float*)(ws + WS_DN);
    float* res   = (float*)(ws + WS_RES);
    float* recon = (float*)(ws + WS_RECON);
    float* fm    = (float*)(ws + WS_FM);
    unsigned long long* part = (unsigned long long*)(ws + WS_PART);
    float* out   = (float*)d_out;

    hipLaunchKernelGGL(k_norm, dim3(A / 4), dim3(256), 0, stream, d, dn);
    hipLaunchKernelGGL(k_init, dim3(2048), dim3(256), 0, stream, x, res, recon, fm);
    hipLaunchKernelGGL(k_conv, dim3(A / 16, B), dim3(320), 0, stream, res, dn, fm);

    void* args[] = { (void*)&dn, (void*)&res, (void*)&recon, (void*)&fm, (void*)&part };
    hipLaunchCooperativeKernel((const void*)k_iter, dim3(256), dim3(256), args, 0, stream);

    hipLaunchKernelGGL(k_out, dim3(64), dim3(256), 0, stream, recon, out);
}

// Round 4
// 1291.795 us; speedup vs baseline: 2.3329x; 2.3329x over previous
//
#include <hip/hip_runtime.h>

#define B 4
#define C 64
#define T 256
#define A 4096
#define RC 264        // residual columns = T + 8
#define PW 260        // fm position stride (257 real, 3 sentinel)
#define NITER 32
#define NBLK 256      // k_iter blocks
#define ATB 16        // atoms owned per block

// ---------------- workspace layout (bytes) ----------------
#define WS_DN     0            // A*512 f32          = 8,388,608
#define WS_RES    8388608      // B*C*RC f32         =   270,336
#define WS_RECON  8658944      // B*C*RC f32         =   270,336
#define WS_FM     8929280      // B*A*PW f32         = 17,039,360
#define WS_PART   25968640     // 2 bufs * 4 * 256 u64 = 16,384
#define WS_BAR    25985024     // barrier counters (2 KB)

__device__ __forceinline__ unsigned long long packmax(float v, unsigned key) {
    unsigned u = __float_as_uint(v);
    u = (u & 0x80000000u) ? ~u : (u | 0x80000000u);   // monotonic float->uint
    return ((unsigned long long)u << 32) | (unsigned long long)(0xFFFFFFFFu - key);
}

// 2-level tree barrier: 16 leaves x 16 blocks -> root. Counters zeroed by
// k_init each launch; gen is monotone within a launch (targets 1..32).
__device__ __forceinline__ void gridbar(unsigned* bar, int bk, unsigned target) {
    __syncthreads();   // wave 0 drains its vmcnt (incl. threads 0-3's part stores)
    if (threadIdx.x == 0) {
        unsigned* leaf = bar + (bk >> 4) * 16;   // 64B apart
        unsigned* root = bar + 256;
        unsigned* gen  = bar + 272;
        unsigned n = __hip_atomic_fetch_add(leaf, 1u, __ATOMIC_ACQ_REL, __HIP_MEMORY_SCOPE_AGENT);
        if (n == 15u) {
            unsigned m = __hip_atomic_fetch_add(root, 1u, __ATOMIC_ACQ_REL, __HIP_MEMORY_SCOPE_AGENT);
            if (m == 15u) {
                #pragma unroll
                for (int i = 0; i < 16; ++i)
                    __hip_atomic_store(bar + i * 16, 0u, __ATOMIC_RELAXED, __HIP_MEMORY_SCOPE_AGENT);
                __hip_atomic_store(root, 0u, __ATOMIC_RELAXED, __HIP_MEMORY_SCOPE_AGENT);
                __hip_atomic_store(gen, target, __ATOMIC_RELEASE, __HIP_MEMORY_SCOPE_AGENT);
            } else {
                while (__hip_atomic_load(gen, __ATOMIC_ACQUIRE, __HIP_MEMORY_SCOPE_AGENT) < target)
                    __builtin_amdgcn_s_sleep(1);
            }
        } else {
            while (__hip_atomic_load(gen, __ATOMIC_ACQUIRE, __HIP_MEMORY_SCOPE_AGENT) < target)
                __builtin_amdgcn_s_sleep(1);
        }
    }
    __syncthreads();
}

// ---------------- K1: unit-norm the dictionary ----------------
__global__ void k_norm(const float* __restrict__ d, float* __restrict__ dn) {
    const int atom = blockIdx.x * 4 + (threadIdx.x >> 6);
    const int lane = threadIdx.x & 63;
    const float* src = d + atom * 512;
    float4 v0 = ((const float4*)src)[lane * 2];
    float4 v1 = ((const float4*)src)[lane * 2 + 1];
    float s = v0.x*v0.x + v0.y*v0.y + v0.z*v0.z + v0.w*v0.w
            + v1.x*v1.x + v1.y*v1.y + v1.z*v1.z + v1.w*v1.w;
    #pragma unroll
    for (int off = 32; off; off >>= 1) s += __shfl_xor(s, off);
    const float denom = sqrtf(s) + 1e-8f;
    float* dst = dn + atom * 512;
    float4 o0 = make_float4(v0.x/denom, v0.y/denom, v0.z/denom, v0.w/denom);
    float4 o1 = make_float4(v1.x/denom, v1.y/denom, v1.z/denom, v1.w/denom);
    ((float4*)dst)[lane * 2]     = o0;
    ((float4*)dst)[lane * 2 + 1] = o1;
}

// ---------------- K2: init res/recon/fm + zero barrier ----------------
// fm cols 0..255 overwritten by k_conv; col 256 = 0 (pad correlation is 0);
// cols 257..259 = -1e30 sentinels.
__global__ void k_init(const float* __restrict__ x, float* __restrict__ res,
                       float* __restrict__ recon, float* __restrict__ fm,
                       unsigned* __restrict__ bar) {
    if (blockIdx.x == 0)
        for (int i = threadIdx.x; i < 512; i += blockDim.x) bar[i] = 0u;  // FIX: all 512 words
    const int tid = blockIdx.x * blockDim.x + threadIdx.x;
    const int nth = gridDim.x * blockDim.x;
    for (int i = tid; i < B * C * RC; i += nth) {
        const int col = i % RC;
        const int bc  = i / RC;
        res[i]   = (col < T) ? x[bc * T + col] : 0.0f;
        recon[i] = 0.0f;
    }
    for (int i = tid; i < B * A * PW; i += nth) {
        const int col = i % PW;
        fm[i] = (col >= 257) ? -1e30f : 0.0f;
    }
}

// ---------------- K3: full correlation fm[b][a][p], p=0..255 ----------------
__global__ __launch_bounds__(256) void k_conv(const float* __restrict__ res,
                                              const float* __restrict__ dn,
                                              float* __restrict__ fm) {
    __shared__ __align__(16) float lr[16 * 264];
    __shared__ __align__(16) float ld[16 * 16 * 8];
    const int b  = blockIdx.y;
    const int a0 = blockIdx.x * 16;
    const int t  = threadIdx.x;
    const int wv = t >> 6, ln = t & 63;

    float acc[4][4] = {};

    for (int cb = 0; cb < 4; ++cb) {
        const float* rsrc = res + b * C * RC + cb * 16 * RC;
        for (int i = t; i < 16 * 264; i += 256) lr[i] = rsrc[i];
        const float* dsrc = dn + a0 * 512 + cb * 128;
        for (int i = t; i < 2048; i += 256) {
            const int as = i >> 7, rem = i & 127;
            ld[i] = dsrc[as * 512 + rem];
        }
        __syncthreads();
        {
            const int p0 = ln * 4;
            for (int cc = 0; cc < 16; ++cc) {
                const float* r = lr + cc * 264 + p0;
                float rv[12];
                *(float4*)(rv)     = *(const float4*)(r);
                *(float4*)(rv + 4) = *(const float4*)(r + 4);
                *(float4*)(rv + 8) = *(const float4*)(r + 8);
                #pragma unroll
                for (int ai = 0; ai < 4; ++ai) {
                    const float* dp = ld + ((wv * 4 + ai) * 16 + cc) * 8;
                    float dk[8];
                    *(float4*)(dk)     = *(const float4*)(dp);
                    *(float4*)(dk + 4) = *(const float4*)(dp + 4);
                    #pragma unroll
                    for (int pi = 0; pi < 4; ++pi)
                        #pragma unroll
                        for (int kk = 0; kk < 8; ++kk)
                            acc[ai][pi] = fmaf(rv[pi + kk], dk[kk], acc[ai][pi]);
                }
            }
        }
        __syncthreads();
    }

    const int p0 = ln * 4;
    #pragma unroll
    for (int ai = 0; ai < 4; ++ai) {
        float* outp = fm + ((long)b * A + a0 + wv * 4 + ai) * PW + p0;
        float4 o; o.x = acc[ai][0]; o.y = acc[ai][1]; o.z = acc[ai][2]; o.w = acc[ai][3];
        *(float4*)outp = o;
    }
}

// ---------------- K4: fused 32-iteration loop, 1 custom barrier/iter ----------------
// 256 blocks x 512 threads. Block bk owns atoms [bk*16, bk*16+16): its fm rows
// are block-private. Cross-block traffic is only part[] (agent-scope atomics,
// double-buffered by parity). Update: fm[b,a,p] -= val_b * G[a, q_b - p].
__global__ __launch_bounds__(512) void k_iter(const float* __restrict__ dn,
                                              float* __restrict__ recon,
                                              float* __restrict__ fm,
                                              unsigned long long* __restrict__ part,
                                              unsigned* __restrict__ bar) {
    __shared__ __align__(16) float dl[ATB][520];         // own atoms (padded rows)
    __shared__ __align__(16) float wpad[4][64 * 24 + 8]; // zero-padded winner rows
    __shared__ __align__(16) float g[ATB][4][16];        // Gram values
    __shared__ unsigned long long sredw[4][8];
    __shared__ int   watom[4], wpos[4];
    __shared__ float wval[4];

    const int bk = blockIdx.x;
    const int a0 = bk * ATB;
    const int t  = threadIdx.x;
    const int wv = t >> 6, ln = t & 63;

    for (int i = t; i < ATB * 512; i += 512) dl[i >> 9][i & 511] = dn[a0 * 512 + i];
    for (int i = t; i < 4 * (64 * 24 + 8); i += 512) ((float*)wpad)[i] = 0.0f;
    __syncthreads();

#define SCAN_TO(bufidx)                                                            \
    {                                                                              \
        for (int b = 0; b < 4; ++b) {                                              \
            const float4* pf = (const float4*)(fm + ((long)b * A + a0) * PW);      \
            unsigned long long m = 0ull;                                           \
            for (int i = t; i < ATB * PW / 4; i += 512) {                          \
                const float4 v = pf[i];                                            \
                const unsigned e = (unsigned)(a0 * PW + i * 4);                    \
                unsigned long long p0 = packmax(v.x, e);                           \
                unsigned long long p1 = packmax(v.y, e + 1);                       \
                unsigned long long p2 = packmax(v.z, e + 2);                       \
                unsigned long long p3 = packmax(v.w, e + 3);                       \
                if (p1 > p0) p0 = p1;                                              \
                if (p3 > p2) p2 = p3;                                              \
                if (p2 > p0) p0 = p2;                                              \
                if (p0 > m)  m = p0;                                               \
            }                                                                      \
            for (int off = 32; off; off >>= 1) {                                   \
                unsigned long long o = __shfl_xor(m, off);                         \
                if (o > m) m = o;                                                  \
            }                                                                      \
            if (ln == 0) sredw[b][wv] = m;                                         \
        }                                                                          \
        __syncthreads();                                                           \
        if (t < 4) {                                                               \
            unsigned long long mm = sredw[t][0];                                   \
            for (int w2 = 1; w2 < 8; ++w2) if (sredw[t][w2] > mm) mm = sredw[t][w2]; \
            __hip_atomic_store(&part[(bufidx) * 1024 + t * 256 + bk], mm,          \
                               __ATOMIC_RELAXED, __HIP_MEMORY_SCOPE_AGENT);        \
        }                                                                          \
    }

    SCAN_TO(0);
    unsigned gen = 1;
    gridbar(bar, bk, gen); gen++;

    for (int it = 0; it < NITER; ++it) {
        // ---- winner reduce (waves 0-3, redundant per block) ----
        if (wv < 4) {
            const unsigned long long* pp = part + (unsigned)(it & 1) * 1024 + wv * 256;
            unsigned long long m = __hip_atomic_load(&pp[ln], __ATOMIC_RELAXED, __HIP_MEMORY_SCOPE_AGENT);
            unsigned long long o;
            o = __hip_atomic_load(&pp[ln +  64], __ATOMIC_RELAXED, __HIP_MEMORY_SCOPE_AGENT); if (o > m) m = o;
            o = __hip_atomic_load(&pp[ln + 128], __ATOMIC_RELAXED, __HIP_MEMORY_SCOPE_AGENT); if (o > m) m = o;
            o = __hip_atomic_load(&pp[ln + 192], __ATOMIC_RELAXED, __HIP_MEMORY_SCOPE_AGENT); if (o > m) m = o;
            for (int off = 32; off; off >>= 1) {
                unsigned long long s = __shfl_xor(m, off);
                if (s > m) m = s;
            }
            if (ln == 0) {
                const unsigned key = 0xFFFFFFFFu - (unsigned)(m & 0xFFFFFFFFull);
                unsigned uv = (unsigned)(m >> 32);
                uv = (uv & 0x80000000u) ? (uv & 0x7FFFFFFFu) : ~uv;
                watom[wv] = key / PW;
                wpos[wv]  = key % PW;
                wval[wv]  = __uint_as_float(uv);
            }
        }
        __syncthreads();

        // ---- commit recon (blocks 0-3, b = bk) ----
        if (bk < 4) {
            const float cv = wval[bk];
            const float* dw = dn + (long)watom[bk] * 512;
            const int cp = wpos[bk];
            const int e = t;   // 512 threads, 512 elements
            recon[(long)(bk * C + (e >> 3)) * RC + cp + (e & 7)] += cv * dw[e];
        }
        if (it == NITER - 1) break;

        // ---- build zero-padded winner rows ----
        for (int i = t; i < 4 * 512; i += 512) {
            const int b = i >> 9, r = i & 511;
            wpad[b][(r >> 3) * 24 + 8 + (r & 7)] = dn[(long)watom[b] * 512 + r];
        }
        __syncthreads();

        // ---- Gram compute: G[a][di] = sum_c sum_k own[c,k]*w[c, k-(di-7)] ----
        {
            const int a = t >> 5, tt = t & 31;
            const int bb = tt & 3, cg = tt >> 2;    // cg 0..7
            float acc[15];
            #pragma unroll
            for (int i = 0; i < 15; ++i) acc[i] = 0.0f;
            for (int cc = 0; cc < 8; ++cc) {
                const int c = cc * 8 + cg;
                float own[8];
                *(float4*)(own)     = *(const float4*)&dl[a][c * 8];
                *(float4*)(own + 4) = *(const float4*)&dl[a][c * 8 + 4];
                float wr[24];
                const float* wp = &wpad[bb][c * 24];
                *(float4*)(wr)      = *(const float4*)(wp);
                *(float4*)(wr + 4)  = *(const float4*)(wp + 4);
                *(float4*)(wr + 8)  = *(const float4*)(wp + 8);
                *(float4*)(wr + 12) = *(const float4*)(wp + 12);
                *(float4*)(wr + 16) = *(const float4*)(wp + 16);
                *(float4*)(wr + 20) = *(const float4*)(wp + 20);
                #pragma unroll
                for (int di = 0; di < 15; ++di)
                    #pragma unroll
                    for (int k = 0; k < 8; ++k)
                        acc[di] = fmaf(own[k], wr[15 + k - di], acc[di]);
            }
            #pragma unroll
            for (int di = 0; di < 15; ++di) {
                acc[di] += __shfl_xor(acc[di], 4);
                acc[di] += __shfl_xor(acc[di], 8);
                acc[di] += __shfl_xor(acc[di], 16);
            }
            if (cg == 0) {
                #pragma unroll
                for (int di = 0; di < 15; ++di) g[a][bb][di] = acc[di];
            }
        }
        __syncthreads();

        // ---- fm Gram-update: p = q + 7 - di ----
        for (int i = t; i < ATB * 4 * 15; i += 512) {
            const int di = i % 15, r = i / 15;
            const int a = r & 15, b = r >> 4;
            const int p = wpos[b] + 7 - di;
            if (p >= 0 && p <= 256)
                fm[((long)b * A + a0 + a) * PW + p] -= wval[b] * g[a][b][di];
        }
        __syncthreads();

        // ---- rescan own rows -> other part buffer ----
        SCAN_TO((it + 1) & 1);
        gridbar(bar, bk, gen); gen++;
    }
#undef SCAN_TO
}

// ---------------- K7: copy recon[..., :T] to out ----------------
__global__ void k_out(const float* __restrict__ recon, float* __restrict__ out) {
    const int tid = blockIdx.x * blockDim.x + threadIdx.x;
    const int nth = gridDim.x * blockDim.x;
    for (int i = tid; i < B * C * (T / 4); i += nth) {
        const int bc = i >> 6;
        const int c4 = i & 63;
        ((float4*)out)[i] = *(const float4*)&recon[bc * RC + c4 * 4];
    }
}

extern "C" void kernel_launch(void* const* d_in, const int* in_sizes, int n_in,
                              void* d_out, int out_size, void* d_ws, size_t ws_size,
                              hipStream_t stream) {
    const float* x = (const float*)d_in[0];
    const float* d = (const float*)d_in[1];
    char* ws = (char*)d_ws;
    float* dn    = (float*)(ws + WS_DN);
    float* res   = (float*)(ws + WS_RES);
    float* recon = (float*)(ws + WS_RECON);
    float* fm    = (float*)(ws + WS_FM);
    unsigned long long* part = (unsigned long long*)(ws + WS_PART);
    unsigned* bar = (unsigned*)(ws + WS_BAR);
    float* out   = (float*)d_out;

    hipLaunchKernelGGL(k_norm, dim3(A / 4), dim3(256), 0, stream, d, dn);
    hipLaunchKernelGGL(k_init, dim3(2048), dim3(256), 0, stream, x, res, recon, fm, bar);
    hipLaunchKernelGGL(k_conv, dim3(A / 16, B), dim3(256), 0, stream, res, dn, fm);

    void* args[] = { (void*)&dn, (void*)&recon, (void*)&fm, (void*)&part, (void*)&bar };
    hipLaunchCooperativeKernel((const void*)k_iter, dim3(NBLK), dim3(512), args, 0, stream);

    hipLaunchKernelGGL(k_out, dim3(64), dim3(256), 0, stream, recon, out);
}

// Round 5
// 844.228 us; speedup vs baseline: 3.5696x; 1.5301x over previous
//
#include <hip/hip_runtime.h>

#define B 4
#define C 64
#define T 256
#define A 4096
#define RC 264        // residual columns = T + 8
#define PW 260        // fm position stride (257 real, 3 sentinel)
#define NITER 32
#define NBLK 256      // k_iter blocks
#define ATB 16        // atoms owned per k_iter block

// ---------------- workspace layout (bytes) ----------------
#define WS_DN     0            // A*512 f32          = 8,388,608
#define WS_RES    8388608      // B*C*RC f32         =   270,336
#define WS_RECON  8658944      // B*C*RC f32         =   270,336
#define WS_FM     8929280      // B*A*PW f32         = 17,039,360
#define WS_PART   25968640     // part[2][4][256] u64 = 16,384
#define WS_FLAG   25985024     // flag[2][256] u32    =  2,048

__device__ __forceinline__ unsigned long long packmax(float v, unsigned key) {
    unsigned u = __float_as_uint(v);
    u = (u & 0x80000000u) ? ~u : (u | 0x80000000u);   // monotonic float->uint
    return ((unsigned long long)u << 32) | (unsigned long long)(0xFFFFFFFFu - key);
}

// ---------------- K1: unit-norm the dictionary ----------------
__global__ void k_norm(const float* __restrict__ d, float* __restrict__ dn) {
    const int atom = blockIdx.x * 4 + (threadIdx.x >> 6);
    const int lane = threadIdx.x & 63;
    const float* src = d + atom * 512;
    float4 v0 = ((const float4*)src)[lane * 2];
    float4 v1 = ((const float4*)src)[lane * 2 + 1];
    float s = v0.x*v0.x + v0.y*v0.y + v0.z*v0.z + v0.w*v0.w
            + v1.x*v1.x + v1.y*v1.y + v1.z*v1.z + v1.w*v1.w;
    #pragma unroll
    for (int off = 32; off; off >>= 1) s += __shfl_xor(s, off);
    const float denom = sqrtf(s) + 1e-8f;
    float* dst = dn + atom * 512;
    float4 o0 = make_float4(v0.x/denom, v0.y/denom, v0.z/denom, v0.w/denom);
    float4 o1 = make_float4(v1.x/denom, v1.y/denom, v1.z/denom, v1.w/denom);
    ((float4*)dst)[lane * 2]     = o0;
    ((float4*)dst)[lane * 2 + 1] = o1;
}

// ---------------- K2: init res/recon/fm-edge + zero flags ----------------
// k_conv overwrites fm cols 0..255; col 256 = 0 (pad correlation); 257..259 sentinels.
__global__ void k_init(const float* __restrict__ x, float* __restrict__ res,
                       float* __restrict__ recon, float* __restrict__ fm,
                       unsigned* __restrict__ flags) {
    if (blockIdx.x == 0)
        for (int i = threadIdx.x; i < 512; i += blockDim.x) flags[i] = 0u;
    const int tid = blockIdx.x * blockDim.x + threadIdx.x;
    const int nth = gridDim.x * blockDim.x;
    for (int i = tid; i < B * C * RC; i += nth) {
        const int col = i % RC;
        const int bc  = i / RC;
        res[i]   = (col < T) ? x[bc * T + col] : 0.0f;
        recon[i] = 0.0f;
    }
    for (int i = tid; i < B * A; i += nth) {
        float* row = fm + (long)i * PW;
        row[256] = 0.0f;
        row[257] = -1e30f; row[258] = -1e30f; row[259] = -1e30f;
    }
}

// ---------------- K3: full correlation fm[b][a][p], p=0..255 ----------------
// grid (A/32, B), 256 threads. Thread = (slot=t>>5 -> 4 atoms, pg=t&31 -> 8 pos).
__global__ __launch_bounds__(256) void k_conv(const float* __restrict__ res,
                                              const float* __restrict__ dn,
                                              float* __restrict__ fm) {
    __shared__ __align__(16) float lr[16 * 264];       // 16-channel res chunk
    __shared__ __align__(16) float ld[32 * 16 * 8];    // [a_sub][cc][k]
    const int b  = blockIdx.y;
    const int a0 = blockIdx.x * 32;
    const int t  = threadIdx.x;
    const int slot = t >> 5;      // 0..7  -> atoms slot*4 .. slot*4+3
    const int pg   = t & 31;      // 0..31 -> positions pg*8 .. pg*8+7
    const int p0   = pg * 8;

    float acc[4][8] = {};

    for (int cb = 0; cb < 4; ++cb) {
        const float* rsrc = res + b * C * RC + cb * 16 * RC;
        for (int i = t; i < 16 * 264; i += 256) lr[i] = rsrc[i];
        const float* dsrc = dn + (long)a0 * 512 + cb * 128;
        for (int i = t; i < 4096; i += 256)
            ld[i] = dsrc[(long)(i >> 7) * 512 + (i & 127)];
        __syncthreads();

        for (int cc = 0; cc < 16; ++cc) {
            float rv[16];
            const float* r = lr + cc * 264 + p0;
            *(float4*)(rv)      = *(const float4*)(r);
            *(float4*)(rv + 4)  = *(const float4*)(r + 4);
            *(float4*)(rv + 8)  = *(const float4*)(r + 8);
            *(float4*)(rv + 12) = *(const float4*)(r + 12);
            float dk[32];
            #pragma unroll
            for (int ai = 0; ai < 4; ++ai) {
                const float* dp = ld + ((slot * 4 + ai) * 16 + cc) * 8;
                *(float4*)(dk + ai * 8)     = *(const float4*)(dp);
                *(float4*)(dk + ai * 8 + 4) = *(const float4*)(dp + 4);
            }
            #pragma unroll
            for (int ai = 0; ai < 4; ++ai)
                #pragma unroll
                for (int pi = 0; pi < 8; ++pi)
                    #pragma unroll
                    for (int kk = 0; kk < 8; ++kk)
                        acc[ai][pi] = fmaf(rv[pi + kk], dk[ai * 8 + kk], acc[ai][pi]);
        }
        __syncthreads();
    }

    #pragma unroll
    for (int ai = 0; ai < 4; ++ai) {
        float* outp = fm + ((long)b * A + a0 + slot * 4 + ai) * PW + p0;
        *(float4*)(outp)     = *(const float4*)&acc[ai][0];
        *(float4*)(outp + 4) = *(const float4*)&acc[ai][4];
    }
}

// ---------------- K4: fused 32-iteration loop, flag protocol (no barrier) ----------------
// 256 blocks x 512 threads. Block bk owns atoms [bk*16, bk*16+16): fm rows
// block-private. Cross-block: parts + flags, relaxed agent atomics only.
// Producer: store 4 parts -> s_waitcnt vmcnt(0) -> store flag = it+1.
// Consumer: wave 0 sweeps 256 flags >= it+1, then loads 1024 parts, reduces winners.
__global__ __launch_bounds__(512) void k_iter(const float* __restrict__ dn,
                                              float* __restrict__ recon,
                                              float* __restrict__ fm,
                                              unsigned long long* __restrict__ parts,
                                              unsigned* __restrict__ flags) {
    __shared__ __align__(16) float dl[ATB][520];         // own atoms (padded rows)
    __shared__ __align__(16) float wpad[4][64 * 24 + 8]; // zero-padded winner rows
    __shared__ __align__(16) float g[ATB][4][16];        // Gram values
    __shared__ unsigned long long sredw[4][8];
    __shared__ int   watom[4], wpos[4];
    __shared__ float wval[4];

    const int bk = blockIdx.x;
    const int a0 = bk * ATB;
    const int t  = threadIdx.x;
    const int wv = t >> 6, ln = t & 63;

    for (int i = t; i < ATB * 512; i += 512) dl[i >> 9][i & 511] = dn[(long)a0 * 512 + i];
    for (int i = t; i < 4 * (64 * 24 + 8); i += 512) ((float*)wpad)[i] = 0.0f;
    __syncthreads();

#define SCAN_TO(bufidx, flagval)                                                   \
    {                                                                              \
        for (int b = 0; b < 4; ++b) {                                              \
            const float4* pf = (const float4*)(fm + ((long)b * A + a0) * PW);      \
            unsigned long long m = 0ull;                                           \
            for (int i = t; i < ATB * PW / 4; i += 512) {                          \
                const float4 v = pf[i];                                            \
                const unsigned e = (unsigned)(a0 * PW + i * 4);                    \
                unsigned long long q0 = packmax(v.x, e);                           \
                unsigned long long q1 = packmax(v.y, e + 1);                       \
                unsigned long long q2 = packmax(v.z, e + 2);                       \
                unsigned long long q3 = packmax(v.w, e + 3);                       \
                if (q1 > q0) q0 = q1;                                              \
                if (q3 > q2) q2 = q3;                                              \
                if (q2 > q0) q0 = q2;                                              \
                if (q0 > m)  m = q0;                                               \
            }                                                                      \
            for (int off = 32; off; off >>= 1) {                                   \
                unsigned long long o = __shfl_xor(m, off);                         \
                if (o > m) m = o;                                                  \
            }                                                                      \
            if (ln == 0) sredw[b][wv] = m;                                         \
        }                                                                          \
        __syncthreads();                                                           \
        if (t == 0) {                                                              \
            for (int b = 0; b < 4; ++b) {                                          \
                unsigned long long mm = sredw[b][0];                               \
                for (int w2 = 1; w2 < 8; ++w2) if (sredw[b][w2] > mm) mm = sredw[b][w2]; \
                __hip_atomic_store(&parts[((bufidx) * 4 + b) * 256 + bk], mm,      \
                                   __ATOMIC_RELAXED, __HIP_MEMORY_SCOPE_AGENT);    \
            }                                                                      \
            asm volatile("s_waitcnt vmcnt(0)" ::: "memory");                       \
            __hip_atomic_store(&flags[((bufidx) << 8) + bk], (unsigned)(flagval),  \
                               __ATOMIC_RELAXED, __HIP_MEMORY_SCOPE_AGENT);        \
        }                                                                          \
    }

    SCAN_TO(0, 1);

    for (int it = 0; it < NITER; ++it) {
        const int p = it & 1;
        const unsigned tgt = (unsigned)(it + 1);

        // ---- wave 0: sweep flags, load parts, reduce winners ----
        if (wv == 0) {
            const unsigned* fl = flags + (p << 8) + ln * 4;
            for (;;) {
                unsigned f0 = __hip_atomic_load(fl + 0, __ATOMIC_RELAXED, __HIP_MEMORY_SCOPE_AGENT);
                unsigned f1 = __hip_atomic_load(fl + 1, __ATOMIC_RELAXED, __HIP_MEMORY_SCOPE_AGENT);
                unsigned f2 = __hip_atomic_load(fl + 2, __ATOMIC_RELAXED, __HIP_MEMORY_SCOPE_AGENT);
                unsigned f3 = __hip_atomic_load(fl + 3, __ATOMIC_RELAXED, __HIP_MEMORY_SCOPE_AGENT);
                if (__all((f0 >= tgt) && (f1 >= tgt) && (f2 >= tgt) && (f3 >= tgt))) break;
                __builtin_amdgcn_s_sleep(2);
            }
            asm volatile("" ::: "memory");
            unsigned long long w[4];
            #pragma unroll
            for (int b = 0; b < 4; ++b) {
                const unsigned long long* pb = parts + (p * 4 + b) * 256 + ln * 4;
                unsigned long long m0 = __hip_atomic_load(pb + 0, __ATOMIC_RELAXED, __HIP_MEMORY_SCOPE_AGENT);
                unsigned long long m1 = __hip_atomic_load(pb + 1, __ATOMIC_RELAXED, __HIP_MEMORY_SCOPE_AGENT);
                unsigned long long m2 = __hip_atomic_load(pb + 2, __ATOMIC_RELAXED, __HIP_MEMORY_SCOPE_AGENT);
                unsigned long long m3 = __hip_atomic_load(pb + 3, __ATOMIC_RELAXED, __HIP_MEMORY_SCOPE_AGENT);
                if (m1 > m0) m0 = m1;
                if (m3 > m2) m2 = m3;
                if (m2 > m0) m0 = m2;
                w[b] = m0;
            }
            #pragma unroll
            for (int off = 32; off; off >>= 1) {
                #pragma unroll
                for (int b = 0; b < 4; ++b) {
                    unsigned long long o = __shfl_xor(w[b], off);
                    if (o > w[b]) w[b] = o;
                }
            }
            if (ln < 4) {
                const unsigned long long m = w[ln];
                const unsigned key = 0xFFFFFFFFu - (unsigned)(m & 0xFFFFFFFFull);
                unsigned uv = (unsigned)(m >> 32);
                uv = (uv & 0x80000000u) ? (uv & 0x7FFFFFFFu) : ~uv;
                watom[ln] = key / PW;
                wpos[ln]  = key % PW;
                wval[ln]  = __uint_as_float(uv);
            }
        }
        __syncthreads();

        // ---- commit recon (blocks 0-3, b = bk) ----
        if (bk < 4) {
            const float cv = wval[bk];
            const float* dw = dn + (long)watom[bk] * 512;
            const int cp = wpos[bk];
            recon[(long)(bk * C + (t >> 3)) * RC + cp + (t & 7)] += cv * dw[t];
        }
        if (it == NITER - 1) break;

        // ---- build zero-padded winner rows ----
        for (int i = t; i < 4 * 512; i += 512) {
            const int b = i >> 9, r = i & 511;
            wpad[b][(r >> 3) * 24 + 8 + (r & 7)] = dn[(long)watom[b] * 512 + r];
        }
        __syncthreads();

        // ---- Gram: G[a][di] = sum_c sum_k own[c,k]*w[c, k-(di-7)] ----
        {
            const int a = t >> 5, tt = t & 31;
            const int bb = tt & 3, cg = tt >> 2;    // cg 0..7
            float acc[15];
            #pragma unroll
            for (int i = 0; i < 15; ++i) acc[i] = 0.0f;
            for (int cc = 0; cc < 8; ++cc) {
                const int c = cc * 8 + cg;
                float own[8];
                *(float4*)(own)     = *(const float4*)&dl[a][c * 8];
                *(float4*)(own + 4) = *(const float4*)&dl[a][c * 8 + 4];
                float wr[24];
                const float* wp = &wpad[bb][c * 24];
                *(float4*)(wr)      = *(const float4*)(wp);
                *(float4*)(wr + 4)  = *(const float4*)(wp + 4);
                *(float4*)(wr + 8)  = *(const float4*)(wp + 8);
                *(float4*)(wr + 12) = *(const float4*)(wp + 12);
                *(float4*)(wr + 16) = *(const float4*)(wp + 16);
                *(float4*)(wr + 20) = *(const float4*)(wp + 20);
                #pragma unroll
                for (int di = 0; di < 15; ++di)
                    #pragma unroll
                    for (int k = 0; k < 8; ++k)
                        acc[di] = fmaf(own[k], wr[15 + k - di], acc[di]);
            }
            #pragma unroll
            for (int di = 0; di < 15; ++di) {
                acc[di] += __shfl_xor(acc[di], 4);
                acc[di] += __shfl_xor(acc[di], 8);
                acc[di] += __shfl_xor(acc[di], 16);
            }
            if (cg == 0) {
                #pragma unroll
                for (int di = 0; di < 15; ++di) g[a][bb][di] = acc[di];
            }
        }
        __syncthreads();

        // ---- fm Gram-update: p = q + 7 - di ----
        for (int i = t; i < ATB * 4 * 15; i += 512) {
            const int di = i % 15, r = i / 15;
            const int a = r & 15, b = r >> 4;
            const int pp = wpos[b] + 7 - di;
            if (pp >= 0 && pp <= 256)
                fm[((long)b * A + a0 + a) * PW + pp] -= wval[b] * g[a][b][di];
        }
        __syncthreads();

        // ---- rescan own rows -> other buffer, flag = it+2 ----
        SCAN_TO(p ^ 1, it + 2);
    }
#undef SCAN_TO
}

// ---------------- K7: copy recon[..., :T] to out ----------------
__global__ void k_out(const float* __restrict__ recon, float* __restrict__ out) {
    const int tid = blockIdx.x * blockDim.x + threadIdx.x;
    const int nth = gridDim.x * blockDim.x;
    for (int i = tid; i < B * C * (T / 4); i += nth) {
        const int bc = i >> 6;
        const int c4 = i & 63;
        ((float4*)out)[i] = *(const float4*)&recon[bc * RC + c4 * 4];
    }
}

extern "C" void kernel_launch(void* const* d_in, const int* in_sizes, int n_in,
                              void* d_out, int out_size, void* d_ws, size_t ws_size,
                              hipStream_t stream) {
    const float* x = (const float*)d_in[0];
    const float* d = (const float*)d_in[1];
    char* ws = (char*)d_ws;
    float* dn    = (float*)(ws + WS_DN);
    float* res   = (float*)(ws + WS_RES);
    float* recon = (float*)(ws + WS_RECON);
    float* fm    = (float*)(ws + WS_FM);
    unsigned long long* parts = (unsigned long long*)(ws + WS_PART);
    unsigned* flags = (unsigned*)(ws + WS_FLAG);
    float* out   = (float*)d_out;

    hipLaunchKernelGGL(k_norm, dim3(A / 4), dim3(256), 0, stream, d, dn);
    hipLaunchKernelGGL(k_init, dim3(1024), dim3(256), 0, stream, x, res, recon, fm, flags);
    hipLaunchKernelGGL(k_conv, dim3(A / 32, B), dim3(256), 0, stream, res, dn, fm);

    void* args[] = { (void*)&dn, (void*)&recon, (void*)&fm, (void*)&parts, (void*)&flags };
    hipLaunchCooperativeKernel((const void*)k_iter, dim3(NBLK), dim3(512), args, 0, stream);

    hipLaunchKernelGGL(k_out, dim3(64), dim3(256), 0, stream, recon, out);
}